// Round 17
// baseline (265.984 us; speedup 1.0000x reference)
//
#include <hip/hip_runtime.h>
#include <stdint.h>

// x: (32, 256, 58, 58) f32 binary {0,1};  w: (256, 256, 3, 3) f32
// out: (32, 256, 56, 56) f32 = alpha[o]*(2S - 2304)
// R20: champion (R17, 80.2us) + MFMA via __builtin_amdgcn_mfma_i32_32x32x32_i8
// instead of inline asm. Mechanism: VGPR_Count=64 arch with 64 acc regs
// proves accs are AGPR-homed, while the asm "+v" constraint demands arch
// class -> allocator inserts v_accvgpr shuffles (VALUBusy 17% ~= 14us vs
// ~2us of real loop VALU). The builtin lets the compiler home C/D in AGPRs
// natively (zero copies), schedule MFMAs individually around ds_read
// latency, and manage hazards (manual s_nops dropped).
// Everything else byte-frozen at champion. If this is null, 80us is the
// practical floor of this decomposition (128 unified regs/wave pins
// occupancy; setprio null R19; volatile-removal was the last win R17).

#define BATCH 32
#define C_IN 256
#define OCH 256
#define HIN 58
#define WIN2 58
#define HOUT 56
#define WOUT 56
#define TAPS 9
#define WWORDS 8            // 256 channels / 32 bits
#define HWIN (HIN * WIN2)   // 3364
#define HWOUT (HOUT * WOUT) // 3136
#define NPOS (BATCH * HWIN) // 107648

#define AP 144              // LDS bytes per input position (128 ch + 16 pad)

typedef int   i32x4  __attribute__((ext_vector_type(4)));
typedef int   i32x16 __attribute__((ext_vector_type(16)));
typedef float f32x4  __attribute__((ext_vector_type(4)));

// ---------------------------------------------------------------------------
// Kernel 1: bit-pack x. Thread <-> one position, all 8 words (R14, verified).
// ---------------------------------------------------------------------------
__global__ __launch_bounds__(256) void pack_x_kernel(
    const float* __restrict__ x, uint32_t* __restrict__ xp)
{
    int p = blockIdx.x * 256 + threadIdx.x;      // 421 blocks, tail-guarded
    if (p >= NPOS) return;
    int b = p / HWIN;
    int r = p - b * HWIN;
    const float* xb = x + (size_t)b * C_IN * HWIN + r;
    uint32_t w[8];
    #pragma unroll
    for (int k = 0; k < 8; ++k) {
        uint32_t m = 0u;
        #pragma unroll
        for (int j = 0; j < 32; ++j)
            m |= (xb[(size_t)(k * 32 + j) * HWIN] > 0.5f ? 1u : 0u) << j;
        w[k] = m;
    }
    *(uint4*)(xp + (size_t)p * WWORDS)     = make_uint4(w[0], w[1], w[2], w[3]);
    *(uint4*)(xp + (size_t)p * WWORDS + 4) = make_uint4(w[4], w[5], w[6], w[7]);
}

// ---------------------------------------------------------------------------
// Kernel 2: pack weights to i8 {+1,-1}, STEP-MAJOR (unchanged, verified):
//   wq8s[((s*2 + e)*256 + o)*16 + j], s = kh*36 + tap*4 + kb,
//   weight channel c = kh*128 + kb*32 + e*16 + j. Also alpha per o.
// ---------------------------------------------------------------------------
__global__ __launch_bounds__(256) void pack_w8_kernel(
    const float* __restrict__ wt, char* __restrict__ wq8s, float* __restrict__ sA)
{
    int o = blockIdx.x;
    int c = threadIdx.x;
    const float* wb = wt + ((size_t)o * C_IN + c) * TAPS;
    float s = 0.f;
    char sg[TAPS];
    #pragma unroll
    for (int t = 0; t < TAPS; ++t) {
        float v = wb[t];
        s += fabsf(v);
        sg[t] = (v >= 0.0f) ? (char)1 : (char)-1;
    }
    int kh = c >> 7;
    int kb = (c >> 5) & 3;
    int e  = (c >> 4) & 1;
    int j  = c & 15;
    #pragma unroll
    for (int t = 0; t < TAPS; ++t) {
        int st = kh * 36 + t * 4 + kb;
        wq8s[(size_t)((st * 2 + e) * 256 + o) * 16 + j] = sg[t];
    }

    __shared__ float red[256];
    red[c] = s;
    __syncthreads();
    for (int off = 128; off > 0; off >>= 1) {
        if (c < off) red[c] += red[c + off];
        __syncthreads();
    }
    if (c == 0) sA[o] = red[0] / (float)(C_IN * HWIN);
}

// ---------------------------------------------------------------------------
// Kernel 3: main i8-MFMA conv (champion structure, R13/R17). Block = 2
// output rows (M=128: 112 valid) x N=256 o. 8 waves (512 thr), wave = 2M x
// 2N quad of 32x32x32 tiles.
// A: bit->+-1 expand into LDS per K-half (stride AP=144), restaged once at
//    s=36 (the only mid-loop barriers).
// B: registers straight from global (L2-resident), 3-deep prefetch.
// R20: MFMA via builtin (compiler-native AGPR placement + scheduling).
// ---------------------------------------------------------------------------
__global__ __launch_bounds__(512)
void xnor_mfma_kernel(
    const uint32_t* __restrict__ xp, const char* __restrict__ wq8s,
    const float* __restrict__ sA, float* __restrict__ out)
{
    __shared__ __attribute__((aligned(16))) char lds[36864]; // A 33,408 / Cbuf 36,864
    char* Alds = lds;
    float* Cbuf = (float*)lds;                   // epilogue alias

    int blk = blockIdx.x;                        // 0..895
    int b   = blk / 28;                          // 28 row-pairs per image
    int rp  = blk - b * 28;
    int oy0 = rp * 2;
    int tid  = threadIdx.x;
    int wv   = tid >> 6;
    int lane = tid & 63;
    int l31  = lane & 31;
    int e    = lane >> 5;
    int mgrp = wv & 1;                           // M-half of this wave
    int ngrp = wv >> 1;                          // o-group (64 o)

    // Per-lane A-frag base for the wave's 2 M-subtiles (row = l31).
    int baseA[2];
    #pragma unroll
    for (int mi = 0; mi < 2; ++mi) {
        int p = (mgrp * 2 + mi) * 32 + l31;      // 0..127
        int r = (p * 586) >> 15;                 // p/56 exact for p<=127
        int c = p - 56 * r;
        baseA[mi] = (r * 58 + c) * AP + e * 16;
    }
    // B-fragment per-lane base in step-major wq8s; step stride = 8192 B.
    const char* pb = wq8s + ((size_t)e * 256 + (size_t)(ngrp * 64 + l31)) * 16;
    float al0 = sA[ngrp * 64 + l31];
    float al1 = sA[ngrp * 64 + 32 + l31];

    i32x16 acc00 = {0}, acc01 = {0}, acc10 = {0}, acc11 = {0};

// A K-step LDS offset (compile-time under full unroll).
#define KA(s) ((((((s) % 36) >> 2) / 3) * 58 + ((((s) % 36) >> 2) % 3)) * AP + ((s) & 3) * 32)

// Expand bit-packed x into +-1 bytes for K-half KH (multiply-spread,
// verified R9-R19). 464 active threads x 4 rows.
#define STAGE_A(KH)                                                        \
    {                                                                      \
        _Pragma("unroll")                                                  \
        for (int ir = 0; ir < 4; ++ir) {                                   \
            if (tid < 464) {                                               \
                int iw = tid >> 3, c16 = tid & 7;                          \
                uint32_t wvx = xp[((size_t)(b * HIN + oy0 + ir) * WIN2 + iw) * WWORDS \
                                  + (KH) * 4 + (c16 >> 1)];                \
                uint32_t bits = (c16 & 1) ? (wvx >> 16) : (wvx & 0xFFFFu); \
                i32x4 v;                                                   \
                _Pragma("unroll")                                          \
                for (int d = 0; d < 4; ++d) {                              \
                    uint32_t n  = (bits >> (4 * d)) & 0xFu;                \
                    uint32_t sp = (n * 0x204081u) & 0x01010101u;           \
                    v[d] = (int)~(sp * 0xFEu);                             \
                }                                                          \
                *(i32x4*)(Alds + (ir * 58 + iw) * AP + c16 * 16) = v;      \
            }                                                              \
        }                                                                  \
    }

    STAGE_A(0);

    // B prefetch prologue: steps 0,1,2 in registers (3-deep, champion).
    i32x4 rb0[3], rb1[3];
    #pragma unroll
    for (int q = 0; q < 3; ++q) {
        rb0[q] = *(const i32x4*)(pb + (size_t)q * 8192);
        rb1[q] = *(const i32x4*)(pb + (size_t)q * 8192 + 512);
    }
    __syncthreads();

    #pragma unroll
    for (int s = 0; s < 72; ++s) {               // s = kh*36 + tap*4 + kb
        if (s == 36) {                           // half-K A restage: the ONLY
            __syncthreads();                     // mid-loop barriers
            STAGE_A(1);
            __syncthreads();
        }
        const int ka = KA(s);                    // compile-time imm

        i32x4 a0 = *(const i32x4*)(Alds + baseA[0] + ka);
        i32x4 a1 = *(const i32x4*)(Alds + baseA[1] + ka);
        i32x4 b0 = rb0[s % 3];
        i32x4 b1 = rb1[s % 3];
        acc00 = __builtin_amdgcn_mfma_i32_32x32x32_i8(a0, b0, acc00, 0, 0, 0);
        acc01 = __builtin_amdgcn_mfma_i32_32x32x32_i8(a0, b1, acc01, 0, 0, 0);
        acc10 = __builtin_amdgcn_mfma_i32_32x32x32_i8(a1, b0, acc10, 0, 0, 0);
        acc11 = __builtin_amdgcn_mfma_i32_32x32x32_i8(a1, b1, acc11, 0, 0, 0);

        const int s3 = (s + 3 > 71) ? 71 : s + 3;          // tail reload harmless
        rb0[s % 3] = *(const i32x4*)(pb + (size_t)s3 * 8192);
        rb1[s % 3] = *(const i32x4*)(pb + (size_t)s3 * 8192 + 512);
    }

    // Epilogue (verbatim champion, verified): D layout col = l31,
    // row = (reg&3) + 8*(reg>>2) + 4*e. 4 quarter-M phases via Cbuf[o][36].
    size_t ob = ((size_t)b * OCH) * HWOUT + (size_t)oy0 * WOUT;
    #pragma unroll
    for (int q = 0; q < 4; ++q) {
        __syncthreads();
        if (mgrp == (q >> 1)) {
            const int mi = q & 1;
            #pragma unroll
            for (int ni = 0; ni < 2; ++ni) {
                float al = ni ? al1 : al0;
                int o = ngrp * 64 + ni * 32 + l31;
                i32x16 A;
                if (mi == 0 && ni == 0) A = acc00;
                else if (mi == 0)       A = acc01;
                else if (ni == 0)       A = acc10;
                else                    A = acc11;
                #pragma unroll
                for (int g = 0; g < 4; ++g) {
                    f32x4 vv;
                    vv[0] = al * (float)A[4 * g + 0];
                    vv[1] = al * (float)A[4 * g + 1];
                    vv[2] = al * (float)A[4 * g + 2];
                    vv[3] = al * (float)A[4 * g + 3];
                    int pl = g * 8 + 4 * e;                // pos within quarter
                    *(f32x4*)(Cbuf + (size_t)o * 36 + pl) = vv;
                }
            }
        }
        __syncthreads();
        #pragma unroll 1
        for (int i = 0; i < 16; ++i) {           // flush 256 o x 32 pos
            int idx = i * 512 + tid;
            int o = idx >> 5, pl = idx & 31;
            int pg = q * 32 + pl;
            if (pg < 112) {
                int r = (pg >= 56) ? 1 : 0;
                int c = pg - 56 * r;
                out[ob + (size_t)o * HWOUT + r * WOUT + c] = Cbuf[o * 36 + pl];
            }
        }
    }
#undef STAGE_A
#undef KA
}

// ---------------------------------------------------------------------------
extern "C" void kernel_launch(void* const* d_in, const int* in_sizes, int n_in,
                              void* d_out, int out_size, void* d_ws, size_t ws_size,
                              hipStream_t stream)
{
    const float* x  = (const float*)d_in[0];
    const float* wt = (const float*)d_in[1];
    float* out = (float*)d_out;

    char* ws = (char*)d_ws;
    uint32_t* xp   = (uint32_t*)ws;                         // 3,444,736 B
    char*     wq8s = (char*)(ws + 3444736);                 //   589,824 B
    float*    sAp  = (float*)(ws + 3444736 + 589824);       //     1,024 B

    // 1) pack x bits: 421 blocks (tail-guarded)
    pack_x_kernel<<<dim3((NPOS + 255) / 256), dim3(256), 0, stream>>>(x, xp);

    // 2) pack weights to +-1 i8, step-major + alpha
    pack_w8_kernel<<<dim3(OCH), dim3(256), 0, stream>>>(wt, wq8s, sAp);

    // 3) main: 32 images x 28 output-row-pairs, 512 threads (8 waves)
    xnor_mfma_kernel<<<dim3(896), dim3(512), 0, stream>>>(xp, wq8s, sAp, out);
}

// Round 18
// 260.296 us; speedup vs baseline: 1.0219x; 1.0219x over previous
//
#include <hip/hip_runtime.h>
#include <stdint.h>

// x: (32, 256, 58, 58) f32 binary {0,1};  w: (256, 256, 3, 3) f32
// out: (32, 256, 56, 56) f32 = alpha[o]*(2S - 2304)
// R21: CHAMPION RESTORED (R17 byte-exact, 80.2us main / 259.5us bench).
// R20 post-mortem: builtin MFMA regressed to 90-93us — VALU only 17->15
// (copy-tax theory falsified), MfmaUtil 34.6->30 with identical MFMA-busy
// time: the compiler's schedule around the builtin is worse than the
// non-volatile hand-asm. Lever ledger after 17 rounds: B-from-global (+14),
// pack_x coalesce (+4), volatile removal (+6) are the wins; A-prefetch,
// waves_per_eu, 2Mx4N, "+a"/"+v" class pins, setprio, builtin all null or
// regressions. The 128-unified-reg/wave ledger (64 arch + 64 AGPR acc)
// pins 2 blocks/CU; remaining gap to the 30.7us MFMA floor is pinned
// step-latency x occupancy. This is the practical floor of this
// decomposition.

#define BATCH 32
#define C_IN 256
#define OCH 256
#define HIN 58
#define WIN2 58
#define HOUT 56
#define WOUT 56
#define TAPS 9
#define WWORDS 8            // 256 channels / 32 bits
#define HWIN (HIN * WIN2)   // 3364
#define HWOUT (HOUT * WOUT) // 3136
#define NPOS (BATCH * HWIN) // 107648

#define AP 144              // LDS bytes per input position (128 ch + 16 pad:
                            // 16B-slot stride 9 (odd) -> b128 slots rotate, ~conflict-free)

typedef int   i32x4  __attribute__((ext_vector_type(4)));
typedef int   i32x16 __attribute__((ext_vector_type(16)));
typedef float f32x4  __attribute__((ext_vector_type(4)));

// MFMA inline asm (numerics verified R9-R20, absmax 0.0). NON-volatile +
// "+v": deps fully encoded by constraints; scheduler free to interleave
// the 4 independent acc chains across K-steps (R17's verified win).
#define MFMA(acc, va, vb) \
    asm("v_mfma_i32_32x32x32_i8 %0, %1, %2, %0" : "+v"(acc) : "v"(va), "v"(vb))

// ---------------------------------------------------------------------------
// Kernel 1: bit-pack x. Thread <-> one position, all 8 words (R14, verified).
// Reads 256B-coalesced per channel step; writes 32B/lane contiguous.
// ---------------------------------------------------------------------------
__global__ __launch_bounds__(256) void pack_x_kernel(
    const float* __restrict__ x, uint32_t* __restrict__ xp)
{
    int p = blockIdx.x * 256 + threadIdx.x;      // 421 blocks, tail-guarded
    if (p >= NPOS) return;
    int b = p / HWIN;
    int r = p - b * HWIN;
    const float* xb = x + (size_t)b * C_IN * HWIN + r;
    uint32_t w[8];
    #pragma unroll
    for (int k = 0; k < 8; ++k) {
        uint32_t m = 0u;
        #pragma unroll
        for (int j = 0; j < 32; ++j)
            m |= (xb[(size_t)(k * 32 + j) * HWIN] > 0.5f ? 1u : 0u) << j;
        w[k] = m;
    }
    *(uint4*)(xp + (size_t)p * WWORDS)     = make_uint4(w[0], w[1], w[2], w[3]);
    *(uint4*)(xp + (size_t)p * WWORDS + 4) = make_uint4(w[4], w[5], w[6], w[7]);
}

// ---------------------------------------------------------------------------
// Kernel 2: pack weights to i8 {+1,-1}, STEP-MAJOR (unchanged, verified):
//   wq8s[((s*2 + e)*256 + o)*16 + j], s = kh*36 + tap*4 + kb,
//   weight channel c = kh*128 + kb*32 + e*16 + j. Also alpha per o.
// ---------------------------------------------------------------------------
__global__ __launch_bounds__(256) void pack_w8_kernel(
    const float* __restrict__ wt, char* __restrict__ wq8s, float* __restrict__ sA)
{
    int o = blockIdx.x;
    int c = threadIdx.x;
    const float* wb = wt + ((size_t)o * C_IN + c) * TAPS;
    float s = 0.f;
    char sg[TAPS];
    #pragma unroll
    for (int t = 0; t < TAPS; ++t) {
        float v = wb[t];
        s += fabsf(v);
        sg[t] = (v >= 0.0f) ? (char)1 : (char)-1;
    }
    int kh = c >> 7;
    int kb = (c >> 5) & 3;
    int e  = (c >> 4) & 1;
    int j  = c & 15;
    #pragma unroll
    for (int t = 0; t < TAPS; ++t) {
        int st = kh * 36 + t * 4 + kb;
        wq8s[(size_t)((st * 2 + e) * 256 + o) * 16 + j] = sg[t];
    }

    __shared__ float red[256];
    red[c] = s;
    __syncthreads();
    for (int off = 128; off > 0; off >>= 1) {
        if (c < off) red[c] += red[c + off];
        __syncthreads();
    }
    if (c == 0) sA[o] = red[0] / (float)(C_IN * HWIN);
}

// ---------------------------------------------------------------------------
// Kernel 3: main i8-MFMA conv (champion structure, R13/R17). Block = 2
// output rows (M=128: 112 valid) x N=256 o. 8 waves (512 thr), wave = 2M x
// 2N quad of 32x32x32 tiles.
// A: bit->+-1 expand into LDS per K-half (stride AP=144), restaged once at
//    s=36 (the only mid-loop barriers).
// B: registers straight from global (L2-resident), 3-deep prefetch.
// Register ledger: 64 arch VGPR + 64 AGPR acc = 128 unified = exactly
// 2 blocks/CU (4 waves/SIMD). Do not add registers.
// ---------------------------------------------------------------------------
__global__ __launch_bounds__(512)
void xnor_mfma_kernel(
    const uint32_t* __restrict__ xp, const char* __restrict__ wq8s,
    const float* __restrict__ sA, float* __restrict__ out)
{
    __shared__ __attribute__((aligned(16))) char lds[36864]; // A 33,408 / Cbuf 36,864
    char* Alds = lds;
    float* Cbuf = (float*)lds;                   // epilogue alias

    int blk = blockIdx.x;                        // 0..895
    int b   = blk / 28;                          // 28 row-pairs per image
    int rp  = blk - b * 28;
    int oy0 = rp * 2;
    int tid  = threadIdx.x;
    int wv   = tid >> 6;
    int lane = tid & 63;
    int l31  = lane & 31;
    int e    = lane >> 5;
    int mgrp = wv & 1;                           // M-half of this wave
    int ngrp = wv >> 1;                          // o-group (64 o)

    // Per-lane A-frag base for the wave's 2 M-subtiles (row = l31).
    int baseA[2];
    #pragma unroll
    for (int mi = 0; mi < 2; ++mi) {
        int p = (mgrp * 2 + mi) * 32 + l31;      // 0..127
        int r = (p * 586) >> 15;                 // p/56 exact for p<=127
        int c = p - 56 * r;
        baseA[mi] = (r * 58 + c) * AP + e * 16;
    }
    // B-fragment per-lane base in step-major wq8s; step stride = 8192 B.
    const char* pb = wq8s + ((size_t)e * 256 + (size_t)(ngrp * 64 + l31)) * 16;
    float al0 = sA[ngrp * 64 + l31];
    float al1 = sA[ngrp * 64 + 32 + l31];

    i32x16 acc00 = {0}, acc01 = {0}, acc10 = {0}, acc11 = {0};
    asm volatile("" : "+v"(acc00), "+v"(acc01), "+v"(acc10), "+v"(acc11)); // pin init above
    asm volatile("s_nop 7\n\ts_nop 7");          // VALU->MFMA srcC hazard guard

// A K-step LDS offset (compile-time under full unroll).
#define KA(s) ((((((s) % 36) >> 2) / 3) * 58 + ((((s) % 36) >> 2) % 3)) * AP + ((s) & 3) * 32)

// Expand bit-packed x into +-1 bytes for K-half KH (multiply-spread,
// verified R9-R20). 464 active threads x 4 rows.
#define STAGE_A(KH)                                                        \
    {                                                                      \
        _Pragma("unroll")                                                  \
        for (int ir = 0; ir < 4; ++ir) {                                   \
            if (tid < 464) {                                               \
                int iw = tid >> 3, c16 = tid & 7;                          \
                uint32_t wvx = xp[((size_t)(b * HIN + oy0 + ir) * WIN2 + iw) * WWORDS \
                                  + (KH) * 4 + (c16 >> 1)];                \
                uint32_t bits = (c16 & 1) ? (wvx >> 16) : (wvx & 0xFFFFu); \
                i32x4 v;                                                   \
                _Pragma("unroll")                                          \
                for (int d = 0; d < 4; ++d) {                              \
                    uint32_t n  = (bits >> (4 * d)) & 0xFu;                \
                    uint32_t sp = (n * 0x204081u) & 0x01010101u;           \
                    v[d] = (int)~(sp * 0xFEu);                             \
                }                                                          \
                *(i32x4*)(Alds + (ir * 58 + iw) * AP + c16 * 16) = v;      \
            }                                                              \
        }                                                                  \
    }

    STAGE_A(0);

    // B prefetch prologue: steps 0,1,2 in registers (3-deep, champion).
    i32x4 rb0[3], rb1[3];
    #pragma unroll
    for (int q = 0; q < 3; ++q) {
        rb0[q] = *(const i32x4*)(pb + (size_t)q * 8192);
        rb1[q] = *(const i32x4*)(pb + (size_t)q * 8192 + 512);
    }
    __syncthreads();

    #pragma unroll
    for (int s = 0; s < 72; ++s) {               // s = kh*36 + tap*4 + kb
        if (s == 36) {                           // half-K A restage: the ONLY
            __syncthreads();                     // mid-loop barriers
            STAGE_A(1);
            __syncthreads();
        }
        const int ka = KA(s);                    // compile-time imm

        i32x4 a0 = *(const i32x4*)(Alds + baseA[0] + ka);
        i32x4 a1 = *(const i32x4*)(Alds + baseA[1] + ka);
        i32x4 b0 = rb0[s % 3];
        i32x4 b1 = rb1[s % 3];
        MFMA(acc00, a0, b0);
        MFMA(acc01, a0, b1);
        MFMA(acc10, a1, b0);
        MFMA(acc11, a1, b1);

        const int s3 = (s + 3 > 71) ? 71 : s + 3;          // tail reload harmless
        rb0[s % 3] = *(const i32x4*)(pb + (size_t)s3 * 8192);
        rb1[s % 3] = *(const i32x4*)(pb + (size_t)s3 * 8192 + 512);
    }

    asm volatile("s_nop 7\n\ts_nop 7");          // MFMA -> epilogue read guard

    // Epilogue (verified): D layout col = l31,
    // row = (reg&3) + 8*(reg>>2) + 4*e. 4 quarter-M phases via Cbuf[o][36].
    size_t ob = ((size_t)b * OCH) * HWOUT + (size_t)oy0 * WOUT;
    #pragma unroll
    for (int q = 0; q < 4; ++q) {
        __syncthreads();
        if (mgrp == (q >> 1)) {
            const int mi = q & 1;
            #pragma unroll
            for (int ni = 0; ni < 2; ++ni) {
                float al = ni ? al1 : al0;
                int o = ngrp * 64 + ni * 32 + l31;
                i32x16 A;
                if (mi == 0 && ni == 0) A = acc00;
                else if (mi == 0)       A = acc01;
                else if (ni == 0)       A = acc10;
                else                    A = acc11;
                #pragma unroll
                for (int g = 0; g < 4; ++g) {
                    f32x4 vv;
                    vv[0] = al * (float)A[4 * g + 0];
                    vv[1] = al * (float)A[4 * g + 1];
                    vv[2] = al * (float)A[4 * g + 2];
                    vv[3] = al * (float)A[4 * g + 3];
                    int pl = g * 8 + 4 * e;                // pos within quarter
                    *(f32x4*)(Cbuf + (size_t)o * 36 + pl) = vv;
                }
            }
        }
        __syncthreads();
        #pragma unroll 1
        for (int i = 0; i < 16; ++i) {           // flush 256 o x 32 pos
            int idx = i * 512 + tid;
            int o = idx >> 5, pl = idx & 31;
            int pg = q * 32 + pl;
            if (pg < 112) {
                int r = (pg >= 56) ? 1 : 0;
                int c = pg - 56 * r;
                out[ob + (size_t)o * HWOUT + r * WOUT + c] = Cbuf[o * 36 + pl];
            }
        }
    }
#undef STAGE_A
#undef KA
}

// ---------------------------------------------------------------------------
extern "C" void kernel_launch(void* const* d_in, const int* in_sizes, int n_in,
                              void* d_out, int out_size, void* d_ws, size_t ws_size,
                              hipStream_t stream)
{
    const float* x  = (const float*)d_in[0];
    const float* wt = (const float*)d_in[1];
    float* out = (float*)d_out;

    char* ws = (char*)d_ws;
    uint32_t* xp   = (uint32_t*)ws;                         // 3,444,736 B
    char*     wq8s = (char*)(ws + 3444736);                 //   589,824 B
    float*    sAp  = (float*)(ws + 3444736 + 589824);       //     1,024 B

    // 1) pack x bits: 421 blocks (tail-guarded)
    pack_x_kernel<<<dim3((NPOS + 255) / 256), dim3(256), 0, stream>>>(x, xp);

    // 2) pack weights to +-1 i8, step-major + alpha
    pack_w8_kernel<<<dim3(OCH), dim3(256), 0, stream>>>(wt, wq8s, sAp);

    // 3) main: 32 images x 28 output-row-pairs, 512 threads (8 waves)
    xnor_mfma_kernel<<<dim3(896), dim3(512), 0, stream>>>(xp, wq8s, sAp, out);
}